// Round 1
// baseline (6781.923 us; speedup 1.0000x reference)
//
#include <hip/hip_runtime.h>
#include <stdint.h>

typedef unsigned long long u64;

// Problem constants: B=16, R=64 -> 1024 images, 2x64x64 rasterized box masks.
// conv1 (64,2,5,5) VALID -> 64x60x60, pool2 -> 64x30x30
// conv2 (32,64,5,5) VALID -> 32x26x26, pool2 -> 32x13x13, mean -> 32
// fc 32->512, relu.

// Fully fused per-image kernel: one block (448 thr = 7 waves) per image.
// conv1 uses the rectangle-indicator structure: channel = Iy(y)*Ix(x), so
//   conv1[c](y,x) = sum_ch sum_i Iy(y+i) * rc[i](x),  rc[i](x)=sum_j w*Ix(x+j)
// and with prefix sums P[k](x)=sum_{i<k} rc[i](x) each output is one
// subtraction P[b+1](x)-P[a](x) over the contiguous set-bit run [a,b] of Iy's
// 5-bit window. Masks are built with wave-wide __ballot (lane = coordinate).
__global__ __launch_bounds__(448) void fused_conv_kernel(
    const float* __restrict__ bboxes,   // [16][32][4]
    const int*   __restrict__ pairs,    // [16][64][2]
    const float* __restrict__ w1,       // [64][2][5][5]
    const float* __restrict__ b1,       // [64]
    const float* __restrict__ w2,       // [32][64][5][5]
    const float* __restrict__ b2,       // [32]
    float* __restrict__ feat)           // [1024][32]
{
  __shared__ float Pb[4*2*6*60];   // prefix tables, 4 conv1-out ch per chunk
  __shared__ float Xs[4*30*32];    // pooled conv1 activations, rows padded to 32
  __shared__ float Ws[32*101];     // conv2 weights chunk, stride 101 (bank-spread)
  __shared__ float partial[416];

  const int n = blockIdx.x;
  const int t = threadIdx.x;
  const int lane = t & 63;

  // ---- box pair -> scaled boxes -> indicator bitmasks (per-wave ballot) ----
  const int bb = n >> 6, rr_ = n & 63;
  const int p0 = pairs[(bb*64 + rr_)*2 + 0];
  const int p1 = pairs[(bb*64 + rr_)*2 + 1];
  const float* A  = bboxes + (bb*32 + p0)*4;
  const float* Bq = bboxes + (bb*32 + p1)*4;
  const float ax1=A[0],  ay1=A[1],  ax2=A[2],  ay2=A[3];
  const float cx1=Bq[0], cy1=Bq[1], cx2=Bq[2], cy2=Bq[3];
  const float ux1=fminf(ax1,cx1), uy1=fminf(ay1,cy1);
  const float ux2=fmaxf(ax2,cx2), uy2=fmaxf(ay2,cy2);
  const float uw=fmaxf(ux2-ux1,1e-6f), uh=fmaxf(uy2-uy1,1e-6f);
  const float g = (float)lane + 0.5f;
  u64 ixs[2], iys[2];
  {
    float X1=(ax1-ux1)/uw*64.f, X2=(ax2-ux1)/uw*64.f;
    float Y1=(ay1-uy1)/uh*64.f, Y2=(ay2-uy1)/uh*64.f;
    ixs[0] = __ballot(g>=X1 && g<=X2);
    iys[0] = __ballot(g>=Y1 && g<=Y2);
  }
  {
    float X1=(cx1-ux1)/uw*64.f, X2=(cx2-ux1)/uw*64.f;
    float Y1=(cy1-uy1)/uh*64.f, Y2=(cy2-uy1)/uh*64.f;
    ixs[1] = __ballot(g>=X1 && g<=X2);
    iys[1] = __ballot(g>=Y1 && g<=Y2);
  }

  // conv2 job for this thread: output channel c, pooled row py (rows 2py,2py+1)
  const int c  = t & 31;
  const int py = t >> 5;          // valid when t < 416 (32c x 13py)
  const int y0 = 2*py;
  float acc0[26], acc1[26];
  #pragma unroll
  for (int i = 0; i < 26; i++) { acc0[i] = 0.f; acc1[i] = 0.f; }

  for (int ch0 = 0; ch0 < 64; ch0 += 4) {
    // 1) build P for conv1-out channels ch0..ch0+3 (480 columns)
    for (int col = t; col < 480; col += 448) {
      int cidx = col / 120;
      int rem  = col - cidx*120;
      int ch   = rem / 60;
      int x    = rem - ch*60;
      unsigned bits = (unsigned)(ixs[ch] >> x) & 31u;
      const float* wr = w1 + (ch0+cidx)*50 + ch*25;
      float* Pp = Pb + cidx*720 + ch*360 + x;
      float p = 0.f;
      Pp[0] = 0.f;
      #pragma unroll
      for (int i = 0; i < 5; i++) {
        float rcv = 0.f;
        #pragma unroll
        for (int j = 0; j < 5; j++)
          rcv += ((bits >> j) & 1u) ? wr[i*5+j] : 0.f;
        p += rcv;
        Pp[(i+1)*60] = p;
      }
    }
    __syncthreads();

    // 2) pooled conv1 activations for these 4 channels -> Xs (fp32, +bias)
    for (int e = t; e < 3600; e += 448) {
      int cc  = e / 900;
      int rem = e - cc*900;
      int qy  = rem / 30, qx = rem - qy*30;
      float v00=0.f, v01=0.f, v10=0.f, v11=0.f;
      #pragma unroll
      for (int ch = 0; ch < 2; ch++) {
        const float* Pc = Pb + cc*720 + ch*360;
        #pragma unroll
        for (int dy = 0; dy < 2; dy++) {
          int y = 2*qy + dy;
          unsigned m = (unsigned)(iys[ch] >> y) & 31u;
          if (m) {
            int a  = __ffs(m) - 1;
            int bt = 31 - __clz((int)m);
            const float* Pa = Pc + a*60;
            const float* Pz = Pc + (bt+1)*60;
            int x0 = 2*qx;
            float s0 = Pz[x0]   - Pa[x0];
            float s1 = Pz[x0+1] - Pa[x0+1];
            if (dy == 0) { v00 += s0; v01 += s1; }
            else         { v10 += s0; v11 += s1; }
          }
        }
      }
      float mx = fmaxf(fmaxf(v00, v01), fmaxf(v10, v11));
      Xs[cc*960 + qy*32 + qx] = mx + b1[ch0+cc];
    }
    // 3) stage conv2 weights for these 4 input channels
    for (int e = t; e < 3200; e += 448) {
      int cw = e / 100;
      int k  = e - cw*100;
      Ws[cw*101 + k] = w2[cw*1600 + ch0*25 + k];
    }
    __syncthreads();

    // 4) conv2 accumulate: register-tiled row convolution
    if (t < 416) {
      for (int cc = 0; cc < 4; cc++) {
        const float* xbase = Xs + cc*960;
        const float* wbase = Ws + c*101 + cc*25;
        #pragma unroll
        for (int rr = 0; rr < 6; rr++) {
          const float* xr = xbase + (y0 + rr)*32;   // 128B-aligned rows
          float row[30];
          #pragma unroll
          for (int q = 0; q < 7; q++) {
            float4 f4 = ((const float4*)xr)[q];
            row[4*q+0]=f4.x; row[4*q+1]=f4.y; row[4*q+2]=f4.z; row[4*q+3]=f4.w;
          }
          row[28] = xr[28]; row[29] = xr[29];
          if (rr < 5) {                 // output row y0, ki = rr
            const float* wr = wbase + rr*5;
            float w0_=wr[0], w1_=wr[1], w2_=wr[2], w3_=wr[3], w4_=wr[4];
            #pragma unroll
            for (int x = 0; x < 26; x++)
              acc0[x] += w0_*row[x] + w1_*row[x+1] + w2_*row[x+2]
                       + w3_*row[x+3] + w4_*row[x+4];
          }
          if (rr >= 1) {                // output row y0+1, ki = rr-1
            const float* wr = wbase + (rr-1)*5;
            float w0_=wr[0], w1_=wr[1], w2_=wr[2], w3_=wr[3], w4_=wr[4];
            #pragma unroll
            for (int x = 0; x < 26; x++)
              acc1[x] += w0_*row[x] + w1_*row[x+1] + w2_*row[x+2]
                       + w3_*row[x+3] + w4_*row[x+4];
          }
        }
      }
    }
    __syncthreads();
  }

  // 5) 2x2 maxpool over 26x26 -> 13x13, sum rows, then mean + conv2 bias
  if (t < 416) {
    float s = 0.f;
    #pragma unroll
    for (int px = 0; px < 13; px++) {
      float m0 = fmaxf(acc0[2*px], acc0[2*px+1]);
      float m1 = fmaxf(acc1[2*px], acc1[2*px+1]);
      s += fmaxf(m0, m1);
    }
    partial[t] = s;
  }
  __syncthreads();
  if (t < 32) {
    float s = 0.f;
    #pragma unroll
    for (int q = 0; q < 13; q++) s += partial[q*32 + t];
    feat[n*32 + t] = s * (1.f/169.f) + b2[t];
  }
}

// fc: out[n][o] = relu(feat[n] . fc_w[o] + fc_b[o]);  1024 x 512
__global__ __launch_bounds__(256) void fc_kernel(
    const float* __restrict__ feat,   // [1024][32]
    const float* __restrict__ fcw,    // [512][32]
    const float* __restrict__ fcb,    // [512]
    float* __restrict__ out)          // [1024][512]
{
  __shared__ float fs[32];
  const int n = blockIdx.x, t = threadIdx.x;
  if (t < 32) fs[t] = feat[n*32 + t];
  __syncthreads();
  for (int o = t; o < 512; o += 256) {
    const float* wr = fcw + o*32;
    float d = 0.f;
    #pragma unroll
    for (int k = 0; k < 32; k++) d += wr[k] * fs[k];
    out[(u64)n*512 + o] = fmaxf(d + fcb[o], 0.f);
  }
}

extern "C" void kernel_launch(void* const* d_in, const int* in_sizes, int n_in,
                              void* d_out, int out_size, void* d_ws, size_t ws_size,
                              hipStream_t stream) {
  const float* bboxes = (const float*)d_in[0];
  // d_in[1] = num_obj, d_in[2] = num_relation: unused by the reference math
  const int*   pairs  = (const int*)  d_in[3];
  const float* w1     = (const float*)d_in[4];
  const float* b1     = (const float*)d_in[5];
  const float* w2     = (const float*)d_in[6];
  const float* b2     = (const float*)d_in[7];
  const float* fcw    = (const float*)d_in[8];
  const float* fcb    = (const float*)d_in[9];
  float* out  = (float*)d_out;
  float* feat = (float*)d_ws;   // 1024*32 floats = 128 KB scratch

  fused_conv_kernel<<<1024, 448, 0, stream>>>(bboxes, pairs, w1, b1, w2, b2, feat);
  fc_kernel<<<1024, 256, 0, stream>>>(feat, fcw, fcb, out);
}

// Round 2
// 373.738 us; speedup vs baseline: 18.1462x; 18.1462x over previous
//
#include <hip/hip_runtime.h>
#include <stdint.h>

typedef unsigned long long u64;
typedef short v8s __attribute__((ext_vector_type(8)));   // 8 bf16 (4 VGPRs) — MFMA A/B frag
typedef float v4f __attribute__((ext_vector_type(4)));   // MFMA C/D frag

__device__ __forceinline__ unsigned short f2bf_rne(float f) {
  union { float f; unsigned u; } c; c.f = f;
  unsigned u = c.u;
  u += 0x7fffu + ((u >> 16) & 1u);   // round-to-nearest-even
  return (unsigned short)(u >> 16);
}

// Pre-pack conv2 weights to bf16 in k = tap*64 + ch order:
// Wr[c][tap*64+ch] = w2[c][ch][tap]   (w2 layout [32][64][5][5])
__global__ __launch_bounds__(256) void prepack_w2(
    const float* __restrict__ w2, unsigned short* __restrict__ Wr) {
  int idx = blockIdx.x * 256 + threadIdx.x;
  if (idx >= 32 * 1600) return;
  int c = idx / 1600, rem = idx - c * 1600;
  int ch = rem & 63, tap = rem >> 6;
  Wr[idx] = f2bf_rne(w2[(c * 64 + ch) * 25 + tap]);
}

// One block (512 thr = 8 waves) per image. Phases:
//  1) box masks via ballot (lane = pixel coordinate)
//  2) conv1+pool via interval prefix sums -> Xs[y][x][ch] bf16 (LDS, stride 72)
//  3) conv2 as implicit-GEMM bf16 MFMA 16x16x32, K = tap*64+ch, acc in VGPRs
//  4) pool2 + mean + conv2 bias -> feat
__global__ __launch_bounds__(512, 2) void fused_kernel(
    const float* __restrict__ bboxes,   // [16][32][4]
    const int*   __restrict__ pairs,    // [16][64][2]
    const float* __restrict__ w1,       // [64][2][5][5]
    const float* __restrict__ b1,       // [64]
    const unsigned short* __restrict__ Wr, // [32][1600] bf16, k-ordered
    const float* __restrict__ b2,       // [32]
    float* __restrict__ feat)           // [1024][32]
{
  extern __shared__ char smem[];
  // Xs: bf16[900 pixels][72] @0 (129600 B); pixel stride 144 B = 4-bank offset
  // P8: float[8 cout][2 cin][6][60] @129600 (23040 B)
  // Cout: float[32][676] aliases Xs after conv2; partial[416] aliases P8
  unsigned short* Xs = (unsigned short*)smem;
  float* P8      = (float*)(smem + 129600);
  float* Cout    = (float*)smem;
  float* partial = (float*)(smem + 129600);

  const int n = blockIdx.x, t = threadIdx.x;
  const int lane = t & 63, wv = t >> 6;
  const int q = lane >> 4, ln = lane & 15;

  // ---- phase 1: box pair -> indicator bitmasks ----
  const int bb = n >> 6, rr_ = n & 63;
  const int p0 = pairs[(bb * 64 + rr_) * 2 + 0];
  const int p1 = pairs[(bb * 64 + rr_) * 2 + 1];
  const float* A  = bboxes + (bb * 32 + p0) * 4;
  const float* Bq = bboxes + (bb * 32 + p1) * 4;
  const float ax1 = A[0],  ay1 = A[1],  ax2 = A[2],  ay2 = A[3];
  const float cx1 = Bq[0], cy1 = Bq[1], cx2 = Bq[2], cy2 = Bq[3];
  const float ux1 = fminf(ax1, cx1), uy1 = fminf(ay1, cy1);
  const float ux2 = fmaxf(ax2, cx2), uy2 = fmaxf(ay2, cy2);
  const float uw = fmaxf(ux2 - ux1, 1e-6f), uh = fmaxf(uy2 - uy1, 1e-6f);
  const float g = (float)lane + 0.5f;
  u64 ixs[2], iys[2];
  {
    float X1 = (ax1 - ux1) / uw * 64.f, X2 = (ax2 - ux1) / uw * 64.f;
    float Y1 = (ay1 - uy1) / uh * 64.f, Y2 = (ay2 - uy1) / uh * 64.f;
    ixs[0] = __ballot(g >= X1 && g <= X2);
    iys[0] = __ballot(g >= Y1 && g <= Y2);
  }
  {
    float X1 = (cx1 - ux1) / uw * 64.f, X2 = (cx2 - ux1) / uw * 64.f;
    float Y1 = (cy1 - uy1) / uh * 64.f, Y2 = (cy2 - uy1) / uh * 64.f;
    ixs[1] = __ballot(g >= X1 && g <= X2);
    iys[1] = __ballot(g >= Y1 && g <= Y2);
  }

  // ---- phase 2: conv1 (+bias) + maxpool2 -> Xs bf16, 8 output channels/chunk
  for (int c8 = 0; c8 < 8; c8++) {
    // 2a) prefix tables P[cidx][cin]: P[k](x) = sum_{i<k} sum_j w*Ix(x+j)
    for (int e = t; e < 960; e += 512) {
      int x = e % 60; int r = e / 60; int ch = r & 1; int cidx = r >> 1;
      unsigned bits = (unsigned)(ixs[ch] >> x) & 31u;
      const float* wr = w1 + (c8 * 8 + cidx) * 50 + ch * 25;
      float* Pp = P8 + (cidx * 2 + ch) * 360 + x;
      float p = 0.f; Pp[0] = 0.f;
      #pragma unroll
      for (int i = 0; i < 5; i++) {
        float rcv = 0.f;
        #pragma unroll
        for (int j = 0; j < 5; j++)
          rcv += ((bits >> j) & 1u) ? wr[i * 5 + j] : 0.f;
        p += rcv;
        Pp[(i + 1) * 60] = p;
      }
    }
    __syncthreads();
    // 2b) pooled outputs: conv(y,x) = P[b+1](x) - P[a](x) over the set-bit run
    for (int pix = t; pix < 900; pix += 512) {
      int qy = pix / 30, qx = pix - qy * 30, x0 = 2 * qx;
      int oa[2][2], oz[2][2]; bool act[2][2]; bool same[2];
      #pragma unroll
      for (int ch = 0; ch < 2; ch++) {
        #pragma unroll
        for (int dy = 0; dy < 2; dy++) {
          unsigned m = (unsigned)(iys[ch] >> (2 * qy + dy)) & 31u;
          act[ch][dy] = (m != 0);
          oa[ch][dy] = m ? (__ffs(m) - 1) * 60 : 0;
          oz[ch][dy] = m ? (32 - __clz(m)) * 60 : 0;
        }
        same[ch] = act[ch][0] && act[ch][1] &&
                   oa[ch][0] == oa[ch][1] && oz[ch][0] == oz[ch][1];
      }
      unsigned short outv[8];
      #pragma unroll
      for (int cidx = 0; cidx < 8; cidx++) {
        float v00 = 0, v01 = 0, v10 = 0, v11 = 0;
        #pragma unroll
        for (int ch = 0; ch < 2; ch++) {
          const float* Pc = P8 + (cidx * 2 + ch) * 360;
          float d0x = 0.f, d0y = 0.f;
          if (act[ch][0]) {
            float2 pa = *(const float2*)(Pc + oa[ch][0] + x0);
            float2 pz = *(const float2*)(Pc + oz[ch][0] + x0);
            d0x = pz.x - pa.x; d0y = pz.y - pa.y;
            v00 += d0x; v01 += d0y;
          }
          if (act[ch][1]) {
            if (same[ch]) { v10 += d0x; v11 += d0y; }
            else {
              float2 pa = *(const float2*)(Pc + oa[ch][1] + x0);
              float2 pz = *(const float2*)(Pc + oz[ch][1] + x0);
              v10 += pz.x - pa.x; v11 += pz.y - pa.y;
            }
          }
        }
        float mx = fmaxf(fmaxf(v00, v01), fmaxf(v10, v11)) + b1[c8 * 8 + cidx];
        outv[cidx] = f2bf_rne(mx);
      }
      unsigned u0 = (unsigned)outv[0] | ((unsigned)outv[1] << 16);
      unsigned u1 = (unsigned)outv[2] | ((unsigned)outv[3] << 16);
      unsigned u2 = (unsigned)outv[4] | ((unsigned)outv[5] << 16);
      unsigned u3 = (unsigned)outv[6] | ((unsigned)outv[7] << 16);
      uint4 pk; pk.x = u0; pk.y = u1; pk.z = u2; pk.w = u3;
      *(uint4*)(Xs + pix * 72 + c8 * 8) = pk;   // 16B aligned: pix*144 + c8*16
    }
    __syncthreads();
  }

  // ---- phase 3: conv2 implicit-GEMM MFMA ----
  // A-frag (W):  lane holds W[m=ln][k = s*32 + q*8 + j]  (contiguous in Wr)
  // B-frag (Xs): lane holds X[k][n=pixel], 8 consecutive ch at fixed tap
  // D: row(m=out-ch) = q*4+reg, col(n=pixel) = ln
  v4f acc[6][2];
  int pclamp[6]; int baseB[6];
  int cnt = 0;
  #pragma unroll
  for (int it = 0; it < 6; it++) {
    int nt = wv + it * 8;
    if (nt < 43) {
      int p = nt * 16 + ln; if (p > 675) p = 675;   // dup-compute pad pixels
      pclamp[it] = p;
      int y = p / 26, x = p - y * 26;
      baseB[it] = (y * 30 + x) * 144 + q * 16;
      cnt = it + 1;
    } else { pclamp[it] = 0; baseB[it] = 0; }
    acc[it][0] = (v4f)0.f; acc[it][1] = (v4f)0.f;
  }
  const unsigned short* pA0 = Wr + ln * 1600 + q * 8;
  const unsigned short* pA1 = pA0 + 16 * 1600;

  for (int i = 0; i < 5; i++) {            // filter row (runtime loop)
    const int rowoff = i * 4320;           // i*30*144 bytes
    #pragma unroll
    for (int ss = 0; ss < 10; ss++) {      // jt = ss>>1, ch-half = ss&1
      const int s = i * 10 + ss;
      v8s a0 = *(const v8s*)(pA0 + s * 32);   // global, L1/L2-hot
      v8s a1 = *(const v8s*)(pA1 + s * 32);
      const int koff = (ss >> 1) * 144 + (ss & 1) * 64;  // const per unroll
      #pragma unroll
      for (int it = 0; it < 6; it++) {
        if (it < cnt) {
          v8s b = *(const v8s*)(smem + (baseB[it] + rowoff + koff));
          acc[it][0] = __builtin_amdgcn_mfma_f32_16x16x32_bf16(a0, b, acc[it][0], 0, 0, 0);
          acc[it][1] = __builtin_amdgcn_mfma_f32_16x16x32_bf16(a1, b, acc[it][1], 0, 0, 0);
        }
      }
    }
  }
  __syncthreads();   // all waves done reading Xs before aliasing as Cout

  #pragma unroll
  for (int it = 0; it < 6; it++) {
    if (it < cnt) {
      #pragma unroll
      for (int mt = 0; mt < 2; mt++) {
        #pragma unroll
        for (int r = 0; r < 4; r++) {
          int ch = mt * 16 + q * 4 + r;
          Cout[ch * 676 + pclamp[it]] = acc[it][mt][r];  // dup pads write same val
        }
      }
    }
  }
  __syncthreads();

  // ---- phase 4: 2x2 maxpool (26x26 -> 13x13), mean, +bias ----
  if (t < 416) {
    int c = t & 31, py = t >> 5;
    const float* r0 = Cout + c * 676 + (2 * py) * 26;
    const float* r1 = r0 + 26;
    float s = 0.f;
    #pragma unroll
    for (int px = 0; px < 13; px++) {
      float m0 = fmaxf(r0[2 * px], r0[2 * px + 1]);
      float m1 = fmaxf(r1[2 * px], r1[2 * px + 1]);
      s += fmaxf(m0, m1);
    }
    partial[t] = s;
  }
  __syncthreads();
  if (t < 32) {
    float s = 0.f;
    #pragma unroll
    for (int k = 0; k < 13; k++) s += partial[k * 32 + t];
    feat[n * 32 + t] = s * (1.f / 169.f) + b2[t];
  }
}

// fc: out[n][o] = relu(feat[n] . fc_w[o] + fc_b[o]);  1024 x 512, fp32
__global__ __launch_bounds__(256) void fc_kernel(
    const float* __restrict__ feat,   // [1024][32]
    const float* __restrict__ fcw,    // [512][32]
    const float* __restrict__ fcb,    // [512]
    float* __restrict__ out)          // [1024][512]
{
  __shared__ float fs[32];
  const int n = blockIdx.x, t = threadIdx.x;
  if (t < 32) fs[t] = feat[n * 32 + t];
  __syncthreads();
  for (int o = t; o < 512; o += 256) {
    const float* wr = fcw + o * 32;
    float d = 0.f;
    #pragma unroll
    for (int k = 0; k < 32; k++) d += wr[k] * fs[k];
    out[(u64)n * 512 + o] = fmaxf(d + fcb[o], 0.f);
  }
}

extern "C" void kernel_launch(void* const* d_in, const int* in_sizes, int n_in,
                              void* d_out, int out_size, void* d_ws, size_t ws_size,
                              hipStream_t stream) {
  const float* bboxes = (const float*)d_in[0];
  // d_in[1] = num_obj, d_in[2] = num_relation: constants, unused by the math
  const int*   pairs  = (const int*)  d_in[3];
  const float* w1     = (const float*)d_in[4];
  const float* b1     = (const float*)d_in[5];
  const float* w2     = (const float*)d_in[6];
  const float* b2     = (const float*)d_in[7];
  const float* fcw    = (const float*)d_in[8];
  const float* fcb    = (const float*)d_in[9];
  float* out  = (float*)d_out;

  float* feat = (float*)d_ws;                                   // 131072 B
  unsigned short* Wr = (unsigned short*)((char*)d_ws + 131072); // 102400 B

  prepack_w2<<<(32 * 1600 + 255) / 256, 256, 0, stream>>>(w2, Wr);
  fused_kernel<<<1024, 512, 152640, stream>>>(bboxes, pairs, w1, b1, Wr, b2, feat);
  fc_kernel<<<1024, 256, 0, stream>>>(feat, fcw, fcb, out);
}

// Round 3
// 257.625 us; speedup vs baseline: 26.3248x; 1.4507x over previous
//
#include <hip/hip_runtime.h>
#include <stdint.h>

typedef unsigned long long u64;
typedef short v8s __attribute__((ext_vector_type(8)));   // 8 bf16 (4 VGPRs) — MFMA A/B frag
typedef float v4f __attribute__((ext_vector_type(4)));   // MFMA C/D frag

__device__ __forceinline__ unsigned short f2bf_rne(float f) {
  union { float f; unsigned u; } c; c.f = f;
  unsigned u = c.u;
  u += 0x7fffu + ((u >> 16) & 1u);   // round-to-nearest-even
  return (unsigned short)(u >> 16);
}

// Pre-pack conv2 weights to bf16, split-K layout:
// Wr[h*25600 + c*800 + tap*32 + chh] = w2[c][h*32+chh][tap]
__global__ __launch_bounds__(256) void prepack_w2(
    const float* __restrict__ w2, unsigned short* __restrict__ Wr) {
  int idx = blockIdx.x * 256 + threadIdx.x;
  if (idx >= 32 * 1600) return;
  int c = idx / 1600, rem = idx - c * 1600;
  int h = rem / 800, r2 = rem - h * 800;
  int tap = r2 >> 5, chh = r2 & 31;
  Wr[h * 25600 + c * 800 + r2] = f2bf_rne(w2[(c * 64 + h * 32 + chh) * 25 + tap]);
}

// One block (512 thr = 8 waves) per image, fully fused incl. fc.
// LDS (dynamic, 80720 B -> 2 blocks/CU):
//   Xs @0:      bf16[900 pix][34 shorts] (32 ch + pad), pixel stride 68 B.
//               stride/4 = 17 (odd) -> 16 banks, 2 lanes/bank = conflict-free;
//               fragments read as 4-B-aligned dword pairs (ds_read2_b32).
//   P  @61200:  float[8 cout][2 cin][5 rows][61]  (rows 1..5 of prefix; row0==0)
//   Cout (alias Xs): float[16 ch][677] per m-half;  partial/fs alias P.
__global__ __launch_bounds__(512, 4) void fused_kernel(
    const float* __restrict__ bboxes,   // [16][32][4]
    const int*   __restrict__ pairs,    // [16][64][2]
    const float* __restrict__ w1,       // [64][2][5][5]
    const float* __restrict__ b1,       // [64]
    const unsigned short* __restrict__ Wr, // [2][32][800] bf16
    const float* __restrict__ b2,       // [32]
    const float* __restrict__ fcw,      // [512][32]
    const float* __restrict__ fcb,      // [512]
    float* __restrict__ out)            // [1024][512]
{
  extern __shared__ char smem[];
  unsigned short* Xs = (unsigned short*)smem;
  float* P8      = (float*)(smem + 61200);
  float* Cout    = (float*)smem;
  float* partial = (float*)(smem + 61200);
  float* fs      = (float*)(smem + 61200 + 1024);

  const int n = blockIdx.x, t = threadIdx.x;
  const int lane = t & 63, wv = t >> 6;
  const int q = lane >> 4, ln = lane & 15;

  // ---- phase 1: box pair -> indicator bitmasks (lane = coordinate) ----
  const int bb = n >> 6, rr_ = n & 63;
  const int p0 = pairs[(bb * 64 + rr_) * 2 + 0];
  const int p1 = pairs[(bb * 64 + rr_) * 2 + 1];
  const float* A  = bboxes + (bb * 32 + p0) * 4;
  const float* Bq = bboxes + (bb * 32 + p1) * 4;
  const float ax1 = A[0],  ay1 = A[1],  ax2 = A[2],  ay2 = A[3];
  const float cx1 = Bq[0], cy1 = Bq[1], cx2 = Bq[2], cy2 = Bq[3];
  const float ux1 = fminf(ax1, cx1), uy1 = fminf(ay1, cy1);
  const float ux2 = fmaxf(ax2, cx2), uy2 = fmaxf(ay2, cy2);
  const float uw = fmaxf(ux2 - ux1, 1e-6f), uh = fmaxf(uy2 - uy1, 1e-6f);
  const float g = (float)lane + 0.5f;
  u64 ixs[2], iys[2];
  {
    float X1 = (ax1 - ux1) / uw * 64.f, X2 = (ax2 - ux1) / uw * 64.f;
    float Y1 = (ay1 - uy1) / uh * 64.f, Y2 = (ay2 - uy1) / uh * 64.f;
    ixs[0] = __ballot(g >= X1 && g <= X2);
    iys[0] = __ballot(g >= Y1 && g <= Y2);
  }
  {
    float X1 = (cx1 - ux1) / uw * 64.f, X2 = (cx2 - ux1) / uw * 64.f;
    float Y1 = (cy1 - uy1) / uh * 64.f, Y2 = (cy2 - uy1) / uh * 64.f;
    ixs[1] = __ballot(g >= X1 && g <= X2);
    iys[1] = __ballot(g >= Y1 && g <= Y2);
  }

  // ---- conv2 MFMA job setup (n-tiles of 16 pixels, 43 tiles) ----
  v4f acc[6][2];
  int pclamp[6], baseB[6];
  int cnt = 0;
  #pragma unroll
  for (int it = 0; it < 6; it++) {
    int nt = wv + it * 8;
    if (nt < 43) {
      int p = nt * 16 + ln; if (p > 675) p = 675;   // dup-compute pad lanes
      pclamp[it] = p;
      int y = p / 26, x = p - y * 26;
      baseB[it] = (y * 30 + x) * 68 + q * 16;
      cnt = it + 1;
    } else { pclamp[it] = 0; baseB[it] = 0; }
    acc[it][0] = (v4f)0.f; acc[it][1] = (v4f)0.f;
  }

  // ---- split-K passes over input-channel halves ----
  for (int h = 0; h < 2; h++) {
    // phase 2: conv1(+pool) for 32 output channels -> Xs, 4 chunks of 8
    for (int c8 = 0; c8 < 4; c8++) {
      const int cbase = h * 32 + c8 * 8;
      // 2a) prefix tables: P[cidx][ch] rows r=0..4 store prefix through row r
      for (int e = t; e < 960; e += 512) {
        int cidx = e / 120, rem = e - cidx * 120;
        int ch = rem / 60, x = rem - ch * 60;
        unsigned bits = (unsigned)(ixs[ch] >> x) & 31u;
        const float* wr = w1 + (cbase + cidx) * 50 + ch * 25;
        float* Pp = P8 + cidx * 610 + ch * 305 + x;
        float p = 0.f;
        #pragma unroll
        for (int i = 0; i < 5; i++) {
          float rcv = 0.f;
          #pragma unroll
          for (int j = 0; j < 5; j++)
            rcv += ((bits >> j) & 1u) ? wr[i * 5 + j] : 0.f;
          p += rcv;
          Pp[i * 61] = p;
        }
      }
      __syncthreads();   // also separates prev phase-3 reads from 2b's Xs writes
      // 2b) pooled conv1 outputs -> Xs bf16
      float b1v[8];
      #pragma unroll
      for (int i = 0; i < 8; i++) b1v[i] = b1[cbase + i];
      for (int pix = t; pix < 900; pix += 512) {
        int qy = pix / 30, qx = pix - qy * 30;
        int x0f = 2 * qx;
        int zo[2][2], ao[2][2]; bool sub[2][2], act[2][2], same[2];
        #pragma unroll
        for (int ch = 0; ch < 2; ch++) {
          unsigned m0 = (unsigned)(iys[ch] >> (2 * qy)) & 31u;
          unsigned m1 = (unsigned)(iys[ch] >> (2 * qy + 1)) & 31u;
          act[ch][0] = m0 != 0; act[ch][1] = m1 != 0;
          zo[ch][0] = (31 - __clz((int)(m0 | 1u))) * 61;
          zo[ch][1] = (31 - __clz((int)(m1 | 1u))) * 61;
          int a0 = __ffs((int)m0) - 1, a1 = __ffs((int)m1) - 1;
          sub[ch][0] = a0 > 0; ao[ch][0] = (a0 > 0 ? a0 - 1 : 0) * 61;
          sub[ch][1] = a1 > 0; ao[ch][1] = (a1 > 0 ? a1 - 1 : 0) * 61;
          same[ch] = (m0 == m1);
        }
        unsigned outs[4];
        #pragma unroll
        for (int cidx = 0; cidx < 8; cidx++) {
          float v0 = 0.f, v1 = 0.f, w0 = 0.f, w1 = 0.f;
          #pragma unroll
          for (int ch = 0; ch < 2; ch++) {
            const float* Pc = P8 + cidx * 610 + ch * 305 + x0f;
            float z0 = Pc[zo[ch][0]], z1 = Pc[zo[ch][0] + 1];
            float pa0 = Pc[ao[ch][0]], pa1 = Pc[ao[ch][0] + 1];
            float d0 = z0 - (sub[ch][0] ? pa0 : 0.f);
            float d1 = z1 - (sub[ch][0] ? pa1 : 0.f);
            d0 = act[ch][0] ? d0 : 0.f;
            d1 = act[ch][0] ? d1 : 0.f;
            v0 += d0; v1 += d1;
            if (same[ch]) { w0 += d0; w1 += d1; }
            else {
              float e0 = Pc[zo[ch][1]], e1 = Pc[zo[ch][1] + 1];
              float f0 = Pc[ao[ch][1]], f1 = Pc[ao[ch][1] + 1];
              float g0 = e0 - (sub[ch][1] ? f0 : 0.f);
              float g1 = e1 - (sub[ch][1] ? f1 : 0.f);
              w0 += act[ch][1] ? g0 : 0.f;
              w1 += act[ch][1] ? g1 : 0.f;
            }
          }
          float mx = fmaxf(fmaxf(v0, v1), fmaxf(w0, w1)) + b1v[cidx];
          unsigned bf = (unsigned)f2bf_rne(mx);
          if ((cidx & 1) == 0) outs[cidx >> 1] = bf;
          else                 outs[cidx >> 1] |= bf << 16;
        }
        unsigned* xw = (unsigned*)(Xs + pix * 34 + c8 * 8);
        xw[0] = outs[0]; xw[1] = outs[1]; xw[2] = outs[2]; xw[3] = outs[3];
      }
      __syncthreads();
    }

    // phase 3: conv2 implicit-GEMM, K-half = 25 taps x 32 ch
    const unsigned short* pA0 = Wr + h * 25600 + ln * 800 + q * 8;
    const unsigned short* pA1 = pA0 + 16 * 800;
    for (int i = 0; i < 5; i++) {
      const int rowoff = i * 2040;            // i*30*68 bytes
      #pragma unroll
      for (int jt = 0; jt < 5; jt++) {
        const int s = i * 5 + jt;
        v8s a0 = *(const v8s*)(pA0 + s * 32);
        v8s a1 = *(const v8s*)(pA1 + s * 32);
        const int off = rowoff + jt * 68;
        #pragma unroll
        for (int it = 0; it < 6; it++) {
          if (it < cnt) {
            const unsigned* bp = (const unsigned*)(smem + (baseB[it] + off));
            uint4 bv; bv.x = bp[0]; bv.y = bp[1]; bv.z = bp[2]; bv.w = bp[3];
            v8s b = __builtin_bit_cast(v8s, bv);
            acc[it][0] = __builtin_amdgcn_mfma_f32_16x16x32_bf16(a0, b, acc[it][0], 0, 0, 0);
            acc[it][1] = __builtin_amdgcn_mfma_f32_16x16x32_bf16(a1, b, acc[it][1], 0, 0, 0);
          }
        }
      }
    }
  }

  // ---- phase 4: per m-half, pool2 + mean + bias -> fs[32] (LDS) ----
  #pragma unroll
  for (int mt = 0; mt < 2; mt++) {
    __syncthreads();               // prior Xs/Cout readers done
    #pragma unroll
    for (int it = 0; it < 6; it++) {
      if (it < cnt) {
        #pragma unroll
        for (int r = 0; r < 4; r++)
          Cout[(q * 4 + r) * 677 + pclamp[it]] = acc[it][mt][r];
      }
    }
    __syncthreads();
    if (t < 208) {
      int c = t & 15, py = t >> 4;
      const float* r0 = Cout + c * 677 + (2 * py) * 26;
      const float* r1 = r0 + 26;
      float s = 0.f;
      #pragma unroll
      for (int px = 0; px < 13; px++) {
        float m0 = fmaxf(r0[2 * px], r0[2 * px + 1]);
        float m1 = fmaxf(r1[2 * px], r1[2 * px + 1]);
        s += fmaxf(m0, m1);
      }
      partial[t] = s;
    }
    __syncthreads();
    if (t < 16) {
      float s = 0.f;
      #pragma unroll
      for (int k = 0; k < 13; k++) s += partial[k * 16 + t];
      fs[mt * 16 + t] = s * (1.f / 169.f) + b2[mt * 16 + t];
    }
  }
  __syncthreads();

  // ---- phase 5: fc (512 outs, thread t -> out column t), relu ----
  {
    const float* wrow = fcw + t * 32;
    float d = 0.f;
    #pragma unroll
    for (int k = 0; k < 32; k++) d += wrow[k] * fs[k];
    out[(u64)n * 512 + t] = fmaxf(d + fcb[t], 0.f);
  }
}

extern "C" void kernel_launch(void* const* d_in, const int* in_sizes, int n_in,
                              void* d_out, int out_size, void* d_ws, size_t ws_size,
                              hipStream_t stream) {
  const float* bboxes = (const float*)d_in[0];
  // d_in[1] = num_obj, d_in[2] = num_relation: constants, unused by the math
  const int*   pairs  = (const int*)  d_in[3];
  const float* w1     = (const float*)d_in[4];
  const float* b1     = (const float*)d_in[5];
  const float* w2     = (const float*)d_in[6];
  const float* b2     = (const float*)d_in[7];
  const float* fcw    = (const float*)d_in[8];
  const float* fcb    = (const float*)d_in[9];
  float* out = (float*)d_out;

  unsigned short* Wr = (unsigned short*)d_ws;   // 102400 B

  prepack_w2<<<(32 * 1600 + 255) / 256, 256, 0, stream>>>(w2, Wr);
  fused_kernel<<<1024, 512, 80720, stream>>>(bboxes, pairs, w1, b1, Wr, b2,
                                             fcw, fcb, out);
}